// Round 5
// baseline (223.111 us; speedup 1.0000x reference)
//
#include <hip/hip_runtime.h>
#include <hip/hip_fp16.h>
#include <math.h>

using f16    = _Float16;
using f16x8  = __attribute__((ext_vector_type(8))) _Float16;
using f32x16 = __attribute__((ext_vector_type(16))) float;

// ---------------- workspace layout (bytes) ----------------
// x16 : [8][98][98][64] f16, zero ring   = 9,834,496
// ewT : [8*9 taps][kg=8][co=128] 16B     = 1,179,648
// fw16: [128 co2][128 co] f16            =    32,768
// ebT : [8][cq=4][l5=2][rr=16] f32       =     4,096
#define X16_OFF 0
#define EWT_OFF 9834496
#define FW_OFF  11014144
#define EBT_OFF 11046912

__device__ __forceinline__ void gl_lds16(const void* g, void* lds_uniform_base) {
  __builtin_amdgcn_global_load_lds(
      (const __attribute__((address_space(1))) unsigned int*)g,
      (__attribute__((address_space(3))) unsigned int*)lds_uniform_base, 16, 0, 0);
}

// ============ K0: convert/transpose everything ============
__global__ __launch_bounds__(256) void pce_prep(
    const float* __restrict__ x, const float* __restrict__ ew,
    const float* __restrict__ eb, const float* __restrict__ fw,
    char* __restrict__ ws)
{
  int idx = blockIdx.x * 256 + threadIdx.x;
  if (idx < 76832) {                       // x16 position (b, y, xc), zero ring
    int xc = idx % 98;
    int t  = idx / 98;
    int y  = t % 98, bb = t / 98;
    char* dst = ws + X16_OFF + (size_t)idx * 128;
    if (y >= 1 && y <= 96 && xc >= 1 && xc <= 96) {
      const float* s = x + ((size_t)(bb * 64) * 96 + (y - 1)) * 96 + (xc - 1);
#pragma unroll
      for (int j = 0; j < 8; ++j) {
        f16x8 v;
#pragma unroll
        for (int k = 0; k < 8; ++k) v[k] = (f16)s[(size_t)(j * 8 + k) * 9216];
        *(f16x8*)(dst + j * 16) = v;
      }
    } else {
      f16x8 z;
#pragma unroll
      for (int k = 0; k < 8; ++k) z[k] = (f16)0.f;
#pragma unroll
      for (int j = 0; j < 8; ++j) *(f16x8*)(dst + j * 16) = z;
    }
  } else if (idx < 150560) {               // ewT [t][kg][co] 16B chunks
    int i = idx - 76832;
    int co = i & 127, q = (i >> 7) & 7, t = i >> 10;
    int e = t / 9, tap = t - e * 9;
    const float* s = ew + ((size_t)((e * 128 + co) * 64 + q * 8)) * 9 + tap;
    f16x8 v;
#pragma unroll
    for (int j = 0; j < 8; ++j) v[j] = (f16)s[j * 9];
    *(f16x8*)(ws + EWT_OFF + (size_t)i * 16) = v;
  } else if (idx < 152608) {               // fw16
    int j = idx - 150560;
    int pos = j & 15, co2 = j >> 4;
    const float* s = fw + co2 * 128 + pos * 8;
    f16x8 v;
#pragma unroll
    for (int k = 0; k < 8; ++k) v[k] = (f16)s[k];
    *(f16x8*)(ws + FW_OFF + (size_t)j * 16) = v;
  } else if (idx < 153632) {               // ebT[e][cq][l5][rr]
    int k = idx - 152608;
    int rr = k & 15, l5 = (k >> 4) & 1, cq = (k >> 5) & 3, e = k >> 7;
    ((float*)(ws + EBT_OFF))[k] =
        eb[e * 128 + cq * 32 + (rr & 3) + 8 * (rr >> 2) + 4 * l5];
  }
}

// ============ fused main kernel ============
// block = (b, patch, half), XCD-swizzled. 4 waves. Phase 1: A (weights) in
// REGISTERS (double-buffered global loads, no barriers, no cross-wave deps);
// B (xs) in LDS, read-only after one __syncthreads. Phase 2: 1x1 conv from
// comb LDS overlay, lane-contiguous nontemporal stores.
__global__ __launch_bounds__(256, 3) void pce_main(
    const float* __restrict__ rw, const float* __restrict__ rb,
    const float* __restrict__ thrp, const char* __restrict__ ws,
    const float* __restrict__ fb, float* __restrict__ out)
{
  __shared__ char sm[32768];   // xs 23040 (phase 1) / comb 32768 (phase 2)
  const int tid = threadIdx.x;
  const int blk = (blockIdx.x & 7) * 72 + (blockIdx.x >> 3);  // bijective XCD swizzle
  const int b = blk / 72;
  const int r72 = blk - b * 72;
  const int patch = r72 >> 1, half = r72 & 1;
  const int py = patch / 6, px = patch - py * 6;
  const int lane = tid & 63, wv = tid >> 6;
  const int l31 = lane & 31, l5 = lane >> 5;
  const int tx = l31 & 15;

  // ---- border ring (bias only) ----
  {
    const int total = 8 * 128 * 388;
    int base = blk * 690;
#pragma unroll 1
    for (int t = tid; t < 690; t += 256) {
      int idx = base + t;
      if (idx < total) {
        int seg = idx % 388;
        int bc = idx / 388;
        int co = bc & 127, bb = bc >> 7;
        int hh, wc;
        if      (seg < 98)  { hh = 0;             wc = seg; }
        else if (seg < 196) { hh = 97;            wc = seg - 98; }
        else if (seg < 292) { hh = seg - 196 + 1; wc = 0; }
        else                { hh = seg - 292 + 1; wc = 97; }
        __builtin_nontemporal_store(fb[co],
            out + ((size_t)(bb * 128 + co) * 98 + hh) * 98 + wc);
      }
    }
  }

  // ---- gates: all registers ----
  unsigned mask;
  float garr[8];
  {
    float sy[8], cy[8], sx[8], cx[8];
    float pyc = ((float)py + 0.5f) * (1.f / 6.f);
    float pxc = ((float)px + 0.5f) * (1.f / 6.f);
#pragma unroll
    for (int k = 0; k < 8; ++k) {
      float fr = (float)(1 << k) * 3.14159265358979323846f;
      sy[k] = sinf(pyc * fr); cy[k] = cosf(pyc * fr);
      sx[k] = sinf(pxc * fr); cx[k] = cosf(pxc * fr);
    }
    float thr = thrp[0];
    unsigned m = 0;
#pragma unroll
    for (int e = 0; e < 8; ++e) {
      float l = rb[e];
#pragma unroll
      for (int k = 0; k < 8; ++k) {
        l = fmaf(sy[k], rw[e * 32 + k],      l);
        l = fmaf(cy[k], rw[e * 32 + 8 + k],  l);
        l = fmaf(sx[k], rw[e * 32 + 16 + k], l);
        l = fmaf(cx[k], rw[e * 32 + 24 + k], l);
      }
      float g = 1.f / (1.f + expf(-l));
      g = (g > thr) ? g : 0.f;
      garr[e] = g;
      m |= (g != 0.f ? 1u : 0u) << e;
    }
    mask = (unsigned)__builtin_amdgcn_readfirstlane((int)m);
  }
  auto pick_g = [&](int ee) {
    float v = garr[0];
#pragma unroll
    for (int k = 1; k < 8; ++k) v = (ee == k) ? garr[k] : v;
    return v;
  };

  // ---- stage xs via global_load_lds (pre-swizzled source, linear dest) ----
  {
    const char* x16 = ws + X16_OFF;
    const int ybase = py * 16 + half * 8;   // padded coords
    const int xbase = px * 16;
#pragma unroll
    for (int itr = 0; itr < 6; ++itr) {
      int ch = tid + itr * 256;
      if (ch < 1440) {
        int j = ch & 7, p = ch >> 3;
        int r = p / 18, c = p - r * 18;
        const char* src = x16 + ((size_t)((b * 98 + ybase + r) * 98 + xbase + c)) * 128
                        + ((j ^ (c & 7)) << 4);
        gl_lds16(src, sm + (itr * 256 + wv * 64) * 16);
      }
    }
  }

  // ---- phase 1: A in registers, barrier-free expert loop ----
  const int m0 = (wv & 1) * 64;              // co half (wave pairs share -> L1)
  const int n0 = (wv >> 1) * 64;             // px quarter
  const int tyb0 = (n0 >> 4) + (l31 >> 4);

  const char* ewt = ws + EWT_OFF;
  f16x8 A0[2][4], A1[2][4];
  f32x16 acc[2][2];
  __half2 comb[2][2][8];
#pragma unroll
  for (int mi = 0; mi < 2; ++mi)
#pragma unroll
    for (int ni = 0; ni < 2; ++ni)
#pragma unroll
      for (int h = 0; h < 8; ++h) comb[mi][ni][h] = __floats2half2_rn(0.f, 0.f);

  auto LDA = [&](f16x8 (&A)[2][4], int t) {
    const char* s = ewt + (size_t)t * 16384;
#pragma unroll
    for (int mi = 0; mi < 2; ++mi)
#pragma unroll
      for (int ks = 0; ks < 4; ++ks)
        A[mi][ks] = *(const f16x8*)(s + ((ks * 2 + l5) * 128 + m0 + mi * 32 + l31) * 16);
  };
  auto TAP = [&](int ky, int kx, const f16x8 (&A)[2][4]) {
    const int cc = tx + kx, sw = cc & 7;
    const int b0 = ((tyb0 + ky) * 18 + cc) << 3;
    const int b1 = ((tyb0 + 2 + ky) * 18 + cc) << 3;
#pragma unroll
    for (int ks = 0; ks < 4; ++ks) {
      const int kg = (ks << 1) | l5;
      f16x8 b0v = *(const f16x8*)(sm + ((b0 + (kg ^ sw)) << 4));
      f16x8 b1v = *(const f16x8*)(sm + ((b1 + (kg ^ sw)) << 4));
      acc[0][0] = __builtin_amdgcn_mfma_f32_32x32x16_f16(A[0][ks], b0v, acc[0][0], 0, 0, 0);
      acc[0][1] = __builtin_amdgcn_mfma_f32_32x32x16_f16(A[0][ks], b1v, acc[0][1], 0, 0, 0);
      acc[1][0] = __builtin_amdgcn_mfma_f32_32x32x16_f16(A[1][ks], b0v, acc[1][0], 0, 0, 0);
      acc[1][1] = __builtin_amdgcn_mfma_f32_32x32x16_f16(A[1][ks], b1v, acc[1][1], 0, 0, 0);
    }
  };

  int e = mask ? (int)__builtin_ctz(mask) : -1;
  if (e >= 0) LDA(A0, e * 9);

  __syncthreads();   // xs staged (drains all waves' own vmcnt, then barrier)

#pragma unroll 1
  while (e >= 0) {
    int nm  = (e < 7) ? (mask >> (e + 1)) : 0;
    int nxt = nm ? e + 1 + (int)__builtin_ctz((unsigned)nm) : -1;
    float g = pick_g(e);

    // acc init = expert bias (pre-transposed to C/D row layout)
#pragma unroll
    for (int mi = 0; mi < 2; ++mi) {
      const int cq = (wv & 1) * 2 + mi;
      const float4* ep = (const float4*)(ws + EBT_OFF + ((e * 4 + cq) * 2 + l5) * 64);
      f32x16 ebv;
#pragma unroll
      for (int q = 0; q < 4; ++q) {
        float4 t = ep[q];
        ebv[4 * q + 0] = t.x; ebv[4 * q + 1] = t.y;
        ebv[4 * q + 2] = t.z; ebv[4 * q + 3] = t.w;
      }
      acc[mi][0] = ebv;
      acc[mi][1] = ebv;
    }

    const int t = e * 9;
    LDA(A1, t + 1); TAP(0, 0, A0);
    LDA(A0, t + 2); TAP(0, 1, A1);
    LDA(A1, t + 3); TAP(0, 2, A0);
    LDA(A0, t + 4); TAP(1, 0, A1);
    LDA(A1, t + 5); TAP(1, 1, A0);
    LDA(A0, t + 6); TAP(1, 2, A1);
    LDA(A1, t + 7); TAP(2, 0, A0);
    LDA(A0, t + 8); TAP(2, 1, A1);
    if (nxt >= 0) LDA(A1, nxt * 9);
    TAP(2, 2, A0);
#pragma unroll
    for (int mi = 0; mi < 2; ++mi)
#pragma unroll
      for (int ks = 0; ks < 4; ++ks) A0[mi][ks] = A1[mi][ks];

    __half2 g2 = __floats2half2_rn(g, g);
#pragma unroll
    for (int mi = 0; mi < 2; ++mi)
#pragma unroll
      for (int ni = 0; ni < 2; ++ni)
#pragma unroll
        for (int h = 0; h < 8; ++h) {
          float v0 = fmaxf(acc[mi][ni][2 * h],     0.f);
          float v1 = fmaxf(acc[mi][ni][2 * h + 1], 0.f);
          comb[mi][ni][h] = __hfma2(g2, __floats2half2_rn(v0, v1), comb[mi][ni][h]);
        }
    e = nxt;
  }

  __syncthreads();   // all waves done reading xs; safe to overlay comb

  // ---- write comb to LDS overlay [128px][128co f16], slot=(co>>3)^(px&15) ----
#pragma unroll
  for (int mi = 0; mi < 2; ++mi)
#pragma unroll
    for (int ni = 0; ni < 2; ++ni) {
      int pxl = n0 + ni * 32 + l31;
      char* rowp = sm + pxl * 256;
      int sw = pxl & 15;
#pragma unroll
      for (int q = 0; q < 4; ++q) {
        int co = m0 + mi * 32 + 8 * q + 4 * l5;
        int off = (((co >> 3) ^ sw) << 4) + (co & 7) * 2;
        uint2 u;
        u.x = *(unsigned*)&comb[mi][ni][2 * q];
        u.y = *(unsigned*)&comb[mi][ni][2 * q + 1];
        *(uint2*)(rowp + off) = u;
      }
    }
  __syncthreads();   // comb visible

  // ---- phase 2: M=co2 (A=fw16 global), N=px (B=comb LDS), K=128 ----
  const int pm0 = (wv & 1) * 64;   // co2 base
  const int pn0 = (wv >> 1) * 64;  // px base
  f32x16 a2[2][2];
#pragma unroll
  for (int mi = 0; mi < 2; ++mi)
#pragma unroll
    for (int ni = 0; ni < 2; ++ni)
#pragma unroll
      for (int rr = 0; rr < 16; ++rr) a2[mi][ni][rr] = 0.f;

  const char* fwp = ws + FW_OFF;
#pragma unroll
  for (int ks = 0; ks < 8; ++ks) {
    const int kg = (ks << 1) | l5;
    f16x8 af[2], bc[2];
#pragma unroll
    for (int mi = 0; mi < 2; ++mi) {
      int co2 = pm0 + mi * 32 + l31;
      af[mi] = *(const f16x8*)(fwp + co2 * 256 + (kg << 4));
    }
#pragma unroll
    for (int ni = 0; ni < 2; ++ni) {
      int pxl = pn0 + ni * 32 + l31;
      bc[ni] = *(const f16x8*)(sm + pxl * 256 + ((kg ^ (pxl & 15)) << 4));
    }
#pragma unroll
    for (int mi = 0; mi < 2; ++mi)
#pragma unroll
      for (int ni = 0; ni < 2; ++ni)
        a2[mi][ni] = __builtin_amdgcn_mfma_f32_32x32x16_f16(af[mi], bc[ni], a2[mi][ni], 0, 0, 0);
  }

  // ---- stores: row = co2, col = px -> lane-contiguous runs, nontemporal ----
#pragma unroll
  for (int mi = 0; mi < 2; ++mi)
#pragma unroll
    for (int rr = 0; rr < 16; ++rr) {
      int co2 = pm0 + mi * 32 + (rr & 3) + 8 * (rr >> 2) + 4 * l5;
      float bias = fb[co2];
      float* obase = out + (size_t)(b * 128 + co2) * 98 * 98;
#pragma unroll
      for (int ni = 0; ni < 2; ++ni) {
        int pxl = pn0 + ni * 32 + l31;
        int y  = py * 16 + half * 8 + (pxl >> 4) + 1;
        int xg = px * 16 + (pxl & 15) + 1;
        __builtin_nontemporal_store(a2[mi][ni][rr] + bias, obase + y * 98 + xg);
      }
    }
}

extern "C" void kernel_launch(void* const* d_in, const int* in_sizes, int n_in,
                              void* d_out, int out_size, void* d_ws, size_t ws_size,
                              hipStream_t stream) {
  const float* x   = (const float*)d_in[0];
  const float* ew  = (const float*)d_in[1];
  const float* ebp = (const float*)d_in[2];
  const float* rw  = (const float*)d_in[3];
  const float* rb  = (const float*)d_in[4];
  const float* fw  = (const float*)d_in[5];
  const float* fb  = (const float*)d_in[6];
  const float* thr = (const float*)d_in[7];
  float* out = (float*)d_out;
  char* ws = (char*)d_ws;

  hipLaunchKernelGGL(pce_prep, dim3(601), dim3(256), 0, stream, x, ew, ebp, fw, ws);
  hipLaunchKernelGGL(pce_main, dim3(576), dim3(256), 0, stream,
                     rw, rb, thr, ws, fb, out);
}

// Round 6
// 150.357 us; speedup vs baseline: 1.4839x; 1.4839x over previous
//
#include <hip/hip_runtime.h>
#include <hip/hip_fp16.h>
#include <math.h>

using f16    = _Float16;
using f16x8  = __attribute__((ext_vector_type(8))) _Float16;
using f32x16 = __attribute__((ext_vector_type(16))) float;

// ---------------- workspace layout (bytes) ----------------
// x16  : [8][98][98][64] f16 zero ring        =  9,834,496
// ewT  : [72 taps][kg 8][co 128] 16B chunks   =  1,179,648
// fwF  : [kg 16][co2 128] 16B chunks          =     32,768
// ebT  : [8][cq 4][l5 2][rr 16] f32           =      4,096
// comb : [8][py 6][yl 16][kg 16][x 96] 16B    = 18,874,368
#define X16_OFF  0
#define EWT_OFF  9834496
#define FWF_OFF  11014144
#define EBT_OFF  11046912
#define COMB_OFF 11051008

// K1 LDS map: xs [10r][18c][8 ci-chunks]16B = 23040 | wb0 16384 | wb1 16384
#define WB0 23040
#define WB1 39424

__device__ __forceinline__ void gl_lds16(const void* g, void* lds_uniform_base) {
  __builtin_amdgcn_global_load_lds(
      (const __attribute__((address_space(1))) unsigned int*)g,
      (__attribute__((address_space(3))) unsigned int*)lds_uniform_base, 16, 0, 0);
}

// ============ K0: border ring + convert/transpose everything ============
__global__ __launch_bounds__(256) void pce_prep(
    const float* __restrict__ x, const float* __restrict__ ew,
    const float* __restrict__ eb, const float* __restrict__ fw,
    const float* __restrict__ fb, float* __restrict__ out,
    char* __restrict__ ws)
{
  int idx = blockIdx.x * 256 + threadIdx.x;
  if (idx < 397312) {                      // output border ring = bias
    int seg = idx % 388;
    int bc  = idx / 388;
    int co  = bc & 127, bb = bc >> 7;
    int hh, wc;
    if      (seg < 98)  { hh = 0;             wc = seg; }
    else if (seg < 196) { hh = 97;            wc = seg - 98; }
    else if (seg < 292) { hh = seg - 196 + 1; wc = 0; }
    else                { hh = seg - 292 + 1; wc = 97; }
    out[((size_t)(bb * 128 + co) * 98 + hh) * 98 + wc] = fb[co];
  } else if (idx < 397312 + 76832) {       // x16 (b,y,xc), zero ring
    int i = idx - 397312;
    int xc = i % 98;
    int t  = i / 98;
    int y  = t % 98, bb = t / 98;
    char* dst = ws + X16_OFF + (size_t)i * 128;
    if (y >= 1 && y <= 96 && xc >= 1 && xc <= 96) {
      const float* s = x + ((size_t)(bb * 64) * 96 + (y - 1)) * 96 + (xc - 1);
#pragma unroll
      for (int j = 0; j < 8; ++j) {
        f16x8 v;
#pragma unroll
        for (int k = 0; k < 8; ++k) v[k] = (f16)s[(size_t)(j * 8 + k) * 9216];
        *(f16x8*)(dst + j * 16) = v;
      }
    } else {
      f16x8 z;
#pragma unroll
      for (int k = 0; k < 8; ++k) z[k] = (f16)0.f;
#pragma unroll
      for (int j = 0; j < 8; ++j) *(f16x8*)(dst + j * 16) = z;
    }
  } else if (idx < 474144 + 73728) {       // ewT [t][kg][co]
    int i = idx - 474144;
    int co = i & 127, q = (i >> 7) & 7, t = i >> 10;
    int e = t / 9, tap = t - e * 9;
    const float* s = ew + ((size_t)((e * 128 + co) * 64 + q * 8)) * 9 + tap;
    f16x8 v;
#pragma unroll
    for (int j = 0; j < 8; ++j) v[j] = (f16)s[j * 9];
    *(f16x8*)(ws + EWT_OFF + (size_t)i * 16) = v;
  } else if (idx < 547872 + 2048) {        // fwF [kg][co2]
    int j = idx - 547872;
    int co2 = j & 127, kg = j >> 7;
    const float* s = fw + co2 * 128 + kg * 8;
    f16x8 v;
#pragma unroll
    for (int k = 0; k < 8; ++k) v[k] = (f16)s[k];
    *(f16x8*)(ws + FWF_OFF + (size_t)j * 16) = v;
  } else if (idx < 549920 + 1024) {        // ebT[e][cq][l5][rr]
    int k = idx - 549920;
    int rr = k & 15, l5 = (k >> 4) & 1, cq = (k >> 5) & 3, e = k >> 7;
    ((float*)(ws + EBT_OFF))[k] =
        eb[e * 128 + cq * 32 + (rr & 3) + 8 * (rr >> 2) + 4 * l5];
  }
}

// ============ K1: gated expert 3x3 convs -> comb (ws) ============
// block = (b, patch, half), 4 waves. W in LDS, double-buffered, counted vmcnt.
__global__ __launch_bounds__(256, 2) void pce_expert(
    const float* __restrict__ rw, const float* __restrict__ rb,
    const float* __restrict__ thrp, char* __restrict__ ws)
{
  __shared__ char sm[55808];
  const int tid = threadIdx.x;
  const int blk = blockIdx.x;
  const int b = blk / 72;
  const int r72 = blk - b * 72;
  const int patch = r72 >> 1, half = r72 & 1;
  const int py = patch / 6, px = patch - py * 6;
  const int lane = tid & 63, wv = tid >> 6;
  const int l31 = lane & 31, l5 = lane >> 5;
  const int tx = l31 & 15;

  // ---- gates in registers ----
  unsigned mask;
  float garr[8];
  {
    float sy[8], cy[8], sx[8], cx[8];
    float pyc = ((float)py + 0.5f) * (1.f / 6.f);
    float pxc = ((float)px + 0.5f) * (1.f / 6.f);
#pragma unroll
    for (int k = 0; k < 8; ++k) {
      float fr = (float)(1 << k) * 3.14159265358979323846f;
      sy[k] = sinf(pyc * fr); cy[k] = cosf(pyc * fr);
      sx[k] = sinf(pxc * fr); cx[k] = cosf(pxc * fr);
    }
    float thr = thrp[0];
    unsigned m = 0;
#pragma unroll
    for (int e = 0; e < 8; ++e) {
      float l = rb[e];
#pragma unroll
      for (int k = 0; k < 8; ++k) {
        l = fmaf(sy[k], rw[e * 32 + k],      l);
        l = fmaf(cy[k], rw[e * 32 + 8 + k],  l);
        l = fmaf(sx[k], rw[e * 32 + 16 + k], l);
        l = fmaf(cx[k], rw[e * 32 + 24 + k], l);
      }
      float g = 1.f / (1.f + expf(-l));
      g = (g > thr) ? g : 0.f;
      garr[e] = g;
      m |= (g != 0.f ? 1u : 0u) << e;
    }
    mask = (unsigned)__builtin_amdgcn_readfirstlane((int)m);
  }
  auto pick_g = [&](int ee) {
    float v = garr[0];
#pragma unroll
    for (int k = 1; k < 8; ++k) v = (ee == k) ? garr[k] : v;
    return v;
  };

  // ---- stage xs (10x18 halo, chunk pos = ci8 ^ (c&7)) via global_load_lds ----
  {
    const char* x16 = ws + X16_OFF;
    const int ybase = py * 16 + half * 8;
    const int xbase = px * 16;
#pragma unroll
    for (int itr = 0; itr < 6; ++itr) {
      int ch = tid + itr * 256;
      if (ch < 1440) {
        int j = ch & 7, p = ch >> 3;
        int r = p / 18, c = p - r * 18;
        const char* src = x16 + ((size_t)((b * 98 + ybase + r) * 98 + xbase + c)) * 128
                        + ((j ^ (c & 7)) << 4);
        gl_lds16(src, sm + (itr * 256 + wv * 64) * 16);
      }
    }
  }

  // ---- prime W tap0 -> wb0 ----
  const int e0 = mask ? (int)__builtin_ctz(mask) : 0;
  {
    const char* s = ws + EWT_OFF + (size_t)(e0 * 9) * 16384;
#pragma unroll
    for (int it = 0; it < 4; ++it)
      gl_lds16(s + (it * 256 + tid) * 16, sm + WB0 + (it * 256 + wv * 64) * 16);
  }

  const int m0 = (wv & 1) * 64;
  const int n0 = (wv >> 1) * 64;
  const int tyb0 = (n0 >> 4) + (l31 >> 4);

  f32x16 acc[2][2];
  __half2 comb[2][2][8];
#pragma unroll
  for (int mi = 0; mi < 2; ++mi)
#pragma unroll
    for (int ni = 0; ni < 2; ++ni)
#pragma unroll
      for (int h = 0; h < 8; ++h) comb[mi][ni][h] = __floats2half2_rn(0.f, 0.f);

  const int T = 9 * __popc(mask);
  int e = e0;
  unsigned rest = mask & ~((2u << e0) - 1u);
  int tap = 0;
  float g_cur = pick_g(e0);

#pragma unroll 1
  for (int tt = 0; tt < T; ++tt) {
    __builtin_amdgcn_s_barrier();   // WAR: all waves done reading wb[(tt+1)&1]

    // prefetch next tap into wb[(tt+1)&1]
    int pe, ptap;
    if (tap < 8) { pe = e; ptap = tap + 1; }
    else         { pe = rest ? (int)__builtin_ctz(rest) : e0; ptap = 0; }
    {
      const char* wsrc = ws + EWT_OFF + (size_t)(pe * 9 + ptap) * 16384;
      char* wdst = sm + ((tt & 1) ? WB0 : WB1);
#pragma unroll
      for (int it = 0; it < 4; ++it)
        gl_lds16(wsrc + (it * 256 + tid) * 16, wdst + (it * 256 + wv * 64) * 16);
    }
    asm volatile("s_waitcnt vmcnt(4)" ::: "memory");  // own prior-tap DMAs retired
    __builtin_amdgcn_s_barrier();                     // everyone's wb[tt&1] valid

    if (tap == 0) {   // acc init = expert bias
#pragma unroll
      for (int mi = 0; mi < 2; ++mi) {
        const int cq = (wv & 1) * 2 + mi;
        const float4* ep = (const float4*)(ws + EBT_OFF + ((e * 4 + cq) * 2 + l5) * 64);
        f32x16 ebv;
#pragma unroll
        for (int q = 0; q < 4; ++q) {
          float4 t4 = ep[q];
          ebv[4 * q + 0] = t4.x; ebv[4 * q + 1] = t4.y;
          ebv[4 * q + 2] = t4.z; ebv[4 * q + 3] = t4.w;
        }
        acc[mi][0] = ebv;
        acc[mi][1] = ebv;
      }
    }

    const char* wcur = sm + ((tt & 1) ? WB1 : WB0);
    const int ky = (tap >= 6) ? 2 : ((tap >= 3) ? 1 : 0);
    const int kx = tap - ky * 3;
    const int cc = tx + kx;
    const int swb = cc & 7;
    const int r0 = ((tyb0 + ky) * 18 + cc) << 3;
    const int r1 = ((tyb0 + 2 + ky) * 18 + cc) << 3;
#pragma unroll
    for (int ks = 0; ks < 4; ++ks) {
      const int kg = (ks << 1) | l5;
      f16x8 a0 = *(const f16x8*)(wcur + ((kg << 7) + m0 + l31) * 16);
      f16x8 a1 = *(const f16x8*)(wcur + ((kg << 7) + m0 + 32 + l31) * 16);
      f16x8 b0 = *(const f16x8*)(sm + ((r0 + (kg ^ swb)) << 4));
      f16x8 b1 = *(const f16x8*)(sm + ((r1 + (kg ^ swb)) << 4));
      acc[0][0] = __builtin_amdgcn_mfma_f32_32x32x16_f16(a0, b0, acc[0][0], 0, 0, 0);
      acc[0][1] = __builtin_amdgcn_mfma_f32_32x32x16_f16(a0, b1, acc[0][1], 0, 0, 0);
      acc[1][0] = __builtin_amdgcn_mfma_f32_32x32x16_f16(a1, b0, acc[1][0], 0, 0, 0);
      acc[1][1] = __builtin_amdgcn_mfma_f32_32x32x16_f16(a1, b1, acc[1][1], 0, 0, 0);
    }

    if (tap == 8) {   // expert epilogue: relu + gate-accumulate
      __half2 g2 = __floats2half2_rn(g_cur, g_cur);
#pragma unroll
      for (int mi = 0; mi < 2; ++mi)
#pragma unroll
        for (int ni = 0; ni < 2; ++ni)
#pragma unroll
          for (int h = 0; h < 8; ++h) {
            float v0 = fmaxf(acc[mi][ni][2 * h],     0.f);
            float v1 = fmaxf(acc[mi][ni][2 * h + 1], 0.f);
            comb[mi][ni][h] = __hfma2(g2, __floats2half2_rn(v0, v1), comb[mi][ni][h]);
          }
      e = pe;
      rest &= rest - 1u;
      g_cur = pick_g(e);
    }
    tap = (tap == 8) ? 0 : tap + 1;
  }

  // ---- store comb -> ws comb[b][py][yl][kg][x] 16B chunks ----
  {
    char* cb = ws + COMB_OFF + (size_t)((b * 6 + py) * 16) * 24576;
#pragma unroll
    for (int mi = 0; mi < 2; ++mi) {
      const int kgb = (m0 + mi * 32) >> 3;
#pragma unroll
      for (int ni = 0; ni < 2; ++ni) {
        int pxl = n0 + ni * 32 + l31;
        int yl = half * 8 + (pxl >> 4);
        int xg = px * 16 + (pxl & 15);
#pragma unroll
        for (int q = 0; q < 4; ++q) {
          uint2 u;
          u.x = *(unsigned*)&comb[mi][ni][2 * q];
          u.y = *(unsigned*)&comb[mi][ni][2 * q + 1];
          *(uint2*)(cb + ((size_t)(yl * 16 + kgb + q) * 96 + xg) * 16 + l5 * 8) = u;
        }
      }
    }
  }
  asm volatile("s_waitcnt vmcnt(0)" ::: "memory");  // drain dead DMA before endpgm
}

// ============ K2: 1x1 conv row-owner GEMM + bias ============
// block = (b, py, co2-quarter). Full 96-wide rows -> contiguous cached stores.
__global__ __launch_bounds__(256, 4) void pce_final(
    const char* __restrict__ ws, const float* __restrict__ fb, float* __restrict__ out)
{
  const int tid = threadIdx.x, blk = blockIdx.x;
  const int b = blk / 24;
  const int r24 = blk - b * 24;
  const int py = r24 >> 2, cq = r24 & 3;
  const int lane = tid & 63, wv = tid >> 6;
  const int l31 = lane & 31, l5 = lane >> 5;

  // A frags (fwF) once: lane l31 -> co2 row
  f16x8 a[8];
#pragma unroll
  for (int ks = 0; ks < 8; ++ks)
    a[ks] = *(const f16x8*)(ws + FWF_OFF + (((ks * 2 + l5) * 128) + cq * 32 + l31) * 16);

  float fbv[16];
#pragma unroll
  for (int rr = 0; rr < 16; ++rr)
    fbv[rr] = fb[cq * 32 + (rr & 3) + 8 * (rr >> 2) + 4 * l5];

  const char* cb = ws + COMB_OFF + (size_t)((b * 6 + py) * 16) * 24576;

#pragma unroll 1
  for (int yi = 0; yi < 4; ++yi) {
    const int yl = wv + yi * 4;
    f32x16 acc[3];
#pragma unroll
    for (int n = 0; n < 3; ++n)
#pragma unroll
      for (int rr = 0; rr < 16; ++rr) acc[n][rr] = 0.f;

#pragma unroll
    for (int ks = 0; ks < 8; ++ks) {
      const char* rowp = cb + (size_t)(yl * 16 + ks * 2 + l5) * 1536;
#pragma unroll
      for (int n = 0; n < 3; ++n) {
        f16x8 bv = *(const f16x8*)(rowp + (n * 32 + l31) * 16);
        acc[n] = __builtin_amdgcn_mfma_f32_32x32x16_f16(a[ks], bv, acc[n], 0, 0, 0);
      }
    }

    const int y = py * 16 + yl + 1;
#pragma unroll
    for (int rr = 0; rr < 16; ++rr) {
      int co2 = cq * 32 + (rr & 3) + 8 * (rr >> 2) + 4 * l5;
      float* op = out + ((size_t)(b * 128 + co2) * 98 + y) * 98 + 1 + l31;
      float bias = fbv[rr];
#pragma unroll
      for (int n = 0; n < 3; ++n) op[n * 32] = acc[n][rr] + bias;
    }
  }
}

extern "C" void kernel_launch(void* const* d_in, const int* in_sizes, int n_in,
                              void* d_out, int out_size, void* d_ws, size_t ws_size,
                              hipStream_t stream) {
  const float* x   = (const float*)d_in[0];
  const float* ew  = (const float*)d_in[1];
  const float* ebp = (const float*)d_in[2];
  const float* rw  = (const float*)d_in[3];
  const float* rb  = (const float*)d_in[4];
  const float* fw  = (const float*)d_in[5];
  const float* fb  = (const float*)d_in[6];
  const float* thr = (const float*)d_in[7];
  float* out = (float*)d_out;
  char* ws = (char*)d_ws;

  hipLaunchKernelGGL(pce_prep,   dim3(2153), dim3(256), 0, stream,
                     x, ew, ebp, fw, fb, out, ws);
  hipLaunchKernelGGL(pce_expert, dim3(576),  dim3(256), 0, stream, rw, rb, thr, ws);
  hipLaunchKernelGGL(pce_final,  dim3(192),  dim3(256), 0, stream, ws, fb, out);
}